// Round 8
// baseline (192.457 us; speedup 1.0000x reference)
//
#include <hip/hip_runtime.h>
#include <cstdint>
#include <cstddef>

// ---------------------------------------------------------------------------
// ChatGPTAttention: x[2,2048,1024] -> QKV proj -> causal MHA (16 heads, dk=64)
//                   -> O proj. bf16 MFMA pipeline, fp32 accumulate.
// Q pre-scaled by 1/8 in QKV-GEMM epilogue; V written transposed there (R14).
// LESSONS: (R5) LDS row stride mult of 8 ushorts. (R6/R8) XOR swizzle for DMA
// LDS. (R11/R15) direct global frags fragment. (R18) split P buffers.
// (R19 FAILED) lag-1 PV spills. (R20 FAILED) direct-global V. (R21 NULL)
// per-CU balancing. (R22 WIN) 4-wave qxkv attn split: 187->179.2, attn ~36.5.
// (R23 NEUTRAL) gemm_bt64 retile. (R24 NEUTRAL) 8-phase gemm8 port ~40us:
// q0 burst 16 reads + lumpy barriers -> LDS-read bound (192 b128 x 12cyc =
// 2300cyc/K-tile/CU vs MFMA 2060cyc); grid 192/256 CUs.
// R25: template-faithful refinement of gemm8:
//  - reads 12/4/8/0 per phase (af-qm0+bf01 | bf23 | af-qm1 | -) so each
//    phase's small read preamble overlaps prior cluster's MFMA drain
//  - ONE vmcnt(2) per K-tile (kt's 8 quarters staged during kt-1; only the
//    2 just-issued kt+1 loads outstanding)
//  - trailing barrier after q0/q1/q2 clusters (lockstep, m196)
//  - bijective XCD swizzle (24-block chunks -> A-panel L2 reuse)
//  - vmcnt(0) drain post-loop (dummy re-stages land before LDS dealloc)
// ---------------------------------------------------------------------------

typedef __attribute__((ext_vector_type(8))) short bf16x8;   // MFMA A/B frag
typedef __attribute__((ext_vector_type(4))) float f32x4;    // MFMA C/D frag
typedef __attribute__((ext_vector_type(4))) unsigned int u32x4;   // 16B copy
typedef __attribute__((ext_vector_type(4))) unsigned short u16x4; // 8B store
typedef __attribute__((ext_vector_type(8))) unsigned short u16x8; // 16B store

__device__ __forceinline__ unsigned short f2b(float f) {  // RNE f32->bf16
  unsigned int u = __float_as_uint(f);
  u = u + 0x7FFFu + ((u >> 16) & 1u);
  return (unsigned short)(u >> 16);
}
__device__ __forceinline__ unsigned short f2b_trunc(float f) {  // truncate
  return (unsigned short)(__float_as_uint(f) >> 16);
}

// async global->LDS DMA, 16B per lane; LDS dest = wave base + lane*16
__device__ __forceinline__ void gl_lds16(const unsigned short* g, unsigned short* s) {
  __builtin_amdgcn_global_load_lds((const __attribute__((address_space(1))) void*)g,
                                   (__attribute__((address_space(3))) void*)s, 16, 0, 0);
}

__device__ __forceinline__ void barrier_mem() {
  asm volatile("" ::: "memory");
  __builtin_amdgcn_s_barrier();
  asm volatile("" ::: "memory");
}

// ---------------- fp32 -> bf16, all three inputs in one launch -------------
__global__ __launch_bounds__(256) void cvt_all(const float* __restrict__ x,
                                               const float* __restrict__ wq,
                                               const float* __restrict__ wo,
                                               unsigned short* __restrict__ xb,
                                               unsigned short* __restrict__ wqb,
                                               unsigned short* __restrict__ wob) {
  const int bid = blockIdx.x;
  const float* in;
  unsigned short* out;
  int base;
  if (bid < 4096)      { in = x;  out = xb;  base = bid; }
  else if (bid < 7168) { in = wq; out = wqb; base = bid - 4096; }
  else                 { in = wo; out = wob; base = bid - 7168; }
  const int idx = (base * 256 + threadIdx.x) * 4;
  f32x4 v = *(const f32x4*)(in + idx);
  u16x4 r;
  r[0] = f2b(v[0]); r[1] = f2b(v[1]); r[2] = f2b(v[2]); r[3] = f2b(v[3]);
  *(u16x4*)(out + idx) = r;
}

// ---------------- QKV GEMM: 4-phase 256x256, BK=64, counted vmcnt ----------
// C[M,N] = (A[M,K] * W[N,K]^T + bias) * colscale; V cols (>=2048) transposed
// into vtb. Grid (12,16) = 192 blocks, 512 threads (8 waves: wm row-half x
// wn col-quarter; wave output 128x64 = acc[8][4]).
__global__ __launch_bounds__(512, 2) void gemm8(const unsigned short* __restrict__ A,
                                                const unsigned short* __restrict__ W,
                                                const float* __restrict__ bias,
                                                unsigned short* __restrict__ Cb,
                                                unsigned short* __restrict__ vtb,
                                                int M, int N, int K, int qcols) {
  __shared__ unsigned short As[2][256 * 64];   // 64KB
  __shared__ unsigned short Bs[2][256 * 64];   // 64KB
  const int tid  = threadIdx.x;
  const int lane = tid & 63;
  const int w    = tid >> 6;            // 8 waves
  const int wm   = w >> 2;              // row half (128 rows)
  const int wn   = w & 3;               // col quarter (64 cols)
  const int l15  = lane & 15, quad = lane >> 4;
  const int xr   = l15 & 7;
  // bijective XCD swizzle: nwg=192=8*24 -> 24-block chunk per XCD
  const int flat = (int)blockIdx.x + 12 * (int)blockIdx.y;
  const int swz  = (flat & 7) * 24 + (flat >> 3);
  const int m0 = (swz / 12) * 256, n0 = (swz % 12) * 256;

  // staging: quarter tile = 64 rows x 64 k = 512 chunks of 16B = 1/thread.
  const int r    = tid >> 3;                    // 0..63 quarter-local row
  const int slot = (tid & 7) ^ (r & 7);         // XOR swizzle (both-sides)
  const unsigned short* gAq = A + (size_t)(m0 + r) * K + slot * 8;
  const unsigned short* gBq = W + (size_t)(n0 + r) * K + slot * 8;
  const int coff = tid * 8;                     // ushort offset in quarter

  f32x4 acc[8][4];
#pragma unroll
  for (int i = 0; i < 8; ++i)
#pragma unroll
    for (int j = 0; j < 4; ++j) acc[i][j] = (f32x4){0.f, 0.f, 0.f, 0.f};

  const size_t q64K = (size_t)64 * K;
  // ---- prologue: stage all 8 quarters of kt0 into buf0 ----
#pragma unroll
  for (int qb = 0; qb < 4; ++qb) {
    gl_lds16(gBq + (size_t)qb * q64K, &Bs[0][qb * 4096 + coff]);
    gl_lds16(gAq + (size_t)qb * q64K, &As[0][qb * 4096 + coff]);
  }

  const int rowA = (wm * 128 + l15) * 64;   // ushort base, qm0 i=0
  const int colB = (wn * 64 + l15) * 64;
  const int NKT = K >> 6;                   // 16 K-tiles

  bf16x8 af[4][2], bf[4][2];
  for (int kt = 0; kt < NKT; ++kt) {
    const int buf = kt & 1;
    const unsigned short* Ab = As[buf];
    const unsigned short* Bb = Bs[buf];
    unsigned short* An = As[buf ^ 1];
    unsigned short* Bn = Bs[buf ^ 1];
    // dummy re-stage into the dead buffer at the last tile (uniform vmcnt)
    const size_t kof = (size_t)((kt + 1 < NKT) ? kt + 1 : NKT - 2) * 64;

    // ---------------- q0: reads af(qm0) 8 + bf j01 4 ----------------
    gl_lds16(gBq + 0 * q64K + kof, &Bn[0 * 4096 + coff]);
    gl_lds16(gBq + 1 * q64K + kof, &Bn[1 * 4096 + coff]);
    asm volatile("s_waitcnt vmcnt(2)" ::: "memory");  // all of kt resident
    barrier_mem();
#pragma unroll
    for (int i = 0; i < 4; ++i)
#pragma unroll
      for (int kc = 0; kc < 2; ++kc)
        af[i][kc] = *(const bf16x8*)&Ab[rowA + i * 1024 + (((kc * 4 + quad) ^ xr) * 8)];
#pragma unroll
    for (int j = 0; j < 2; ++j)
#pragma unroll
      for (int kc = 0; kc < 2; ++kc)
        bf[j][kc] = *(const bf16x8*)&Bb[colB + j * 1024 + (((kc * 4 + quad) ^ xr) * 8)];
    asm volatile("s_waitcnt lgkmcnt(0)" ::: "memory");
    __builtin_amdgcn_sched_barrier(0);
    __builtin_amdgcn_s_setprio(1);
#pragma unroll
    for (int i = 0; i < 4; ++i)
#pragma unroll
      for (int j = 0; j < 2; ++j)
#pragma unroll
        for (int kc = 0; kc < 2; ++kc)
          acc[i][j] = __builtin_amdgcn_mfma_f32_16x16x32_bf16(af[i][kc], bf[j][kc], acc[i][j], 0, 0, 0);
    __builtin_amdgcn_s_setprio(0);
    barrier_mem();
    // ---------------- q1: reads bf j23 4 ----------------
    gl_lds16(gBq + 2 * q64K + kof, &Bn[2 * 4096 + coff]);
    gl_lds16(gBq + 3 * q64K + kof, &Bn[3 * 4096 + coff]);
#pragma unroll
    for (int j = 2; j < 4; ++j)
#pragma unroll
      for (int kc = 0; kc < 2; ++kc)
        bf[j][kc] = *(const bf16x8*)&Bb[colB + j * 1024 + (((kc * 4 + quad) ^ xr) * 8)];
    asm volatile("s_waitcnt lgkmcnt(0)" ::: "memory");
    __builtin_amdgcn_sched_barrier(0);
    __builtin_amdgcn_s_setprio(1);
#pragma unroll
    for (int i = 0; i < 4; ++i)
#pragma unroll
      for (int j = 2; j < 4; ++j)
#pragma unroll
        for (int kc = 0; kc < 2; ++kc)
          acc[i][j] = __builtin_amdgcn_mfma_f32_16x16x32_bf16(af[i][kc], bf[j][kc], acc[i][j], 0, 0, 0);
    __builtin_amdgcn_s_setprio(0);
    barrier_mem();
    // ---------------- q2: reads af(qm1) 8 ----------------
    gl_lds16(gAq + 0 * q64K + kof, &An[0 * 4096 + coff]);
    gl_lds16(gAq + 2 * q64K + kof, &An[2 * 4096 + coff]);
#pragma unroll
    for (int i = 0; i < 4; ++i)
#pragma unroll
      for (int kc = 0; kc < 2; ++kc)
        af[i][kc] = *(const bf16x8*)&Ab[rowA + 4096 + i * 1024 + (((kc * 4 + quad) ^ xr) * 8)];
    asm volatile("s_waitcnt lgkmcnt(0)" ::: "memory");
    __builtin_amdgcn_sched_barrier(0);
    __builtin_amdgcn_s_setprio(1);
#pragma unroll
    for (int i = 0; i < 4; ++i)
#pragma unroll
      for (int j = 2; j < 4; ++j)
#pragma unroll
        for (int kc = 0; kc < 2; ++kc)
          acc[4 + i][j] = __builtin_amdgcn_mfma_f32_16x16x32_bf16(af[i][kc], bf[j][kc], acc[4 + i][j], 0, 0, 0);
    __builtin_amdgcn_s_setprio(0);
    barrier_mem();
    // ---------------- q3: no reads ----------------
    gl_lds16(gAq + 1 * q64K + kof, &An[1 * 4096 + coff]);
    gl_lds16(gAq + 3 * q64K + kof, &An[3 * 4096 + coff]);
    __builtin_amdgcn_s_setprio(1);
#pragma unroll
    for (int i = 0; i < 4; ++i)
#pragma unroll
      for (int j = 0; j < 2; ++j)
#pragma unroll
        for (int kc = 0; kc < 2; ++kc)
          acc[4 + i][j] = __builtin_amdgcn_mfma_f32_16x16x32_bf16(af[i][kc], bf[j][kc], acc[4 + i][j], 0, 0, 0);
    __builtin_amdgcn_s_setprio(0);
    // no trailing barrier: next q0 has vmcnt+barrier
  }
  asm volatile("s_waitcnt vmcnt(0)" ::: "memory");  // drain dummies pre-exit

  // ---- epilogue ----
  const bool vblock = (n0 >= 2048);  // block-uniform (n0 multiple of 256)
#pragma unroll
  for (int i = 0; i < 8; ++i) {
    const int row = m0 + wm * 128 + i * 16 + quad * 4;
#pragma unroll
    for (int j = 0; j < 4; ++j) {
      const int col = n0 + wn * 64 + j * 16 + l15;
      const float bv = bias[col];
      if (!vblock) {
        const float sc = (col < qcols) ? 0.125f : 1.0f;
#pragma unroll
        for (int rr = 0; rr < 4; ++rr)
          Cb[(size_t)(row + rr) * N + col] = f2b((acc[i][j][rr] + bv) * sc);
      } else {
        const int hd = col - 2048;
        const int bb = row >> 11, s = row & 2047;
        u16x4 ov;
#pragma unroll
        for (int rr = 0; rr < 4; ++rr) ov[rr] = f2b(acc[i][j][rr] + bv);
        *(u16x4*)(vtb + ((size_t)(bb * 1024 + hd)) * 2048 + s) = ov;
      }
    }
  }
}

// ---------------- GEMM 128x64 tile, fp32 out (O-projection) ----------------
// R23 config. Grid (16,32)=512 blocks, LDS 48KB.
__global__ __launch_bounds__(256) void gemm_bt64(const unsigned short* __restrict__ A,
                                                 const unsigned short* __restrict__ W,
                                                 const float* __restrict__ bias,
                                                 float* __restrict__ Cf,
                                                 int M, int N, int K) {
  __shared__ unsigned short As[2][128 * 64];
  __shared__ unsigned short Bs[2][64 * 64];
  const int tid  = threadIdx.x;
  const int lane = tid & 63;
  const int w    = tid >> 6;
  const int wy   = w >> 1, wx = w & 1;
  const int l15  = lane & 15, quad = lane >> 4;
  const int xr   = l15 & 7;
  const int m0 = blockIdx.y * 128, n0 = blockIdx.x * 64;

  const unsigned short* gA[4];
  int offA[4];
#pragma unroll
  for (int p = 0; p < 4; ++p) {
    const int c = tid + p * 256;
    const int r = c >> 3;
    const int sc = ((c & 7) ^ (r & 7)) * 8;
    gA[p] = A + (size_t)(m0 + r) * K + sc;
    offA[p] = c * 8;
  }
  const unsigned short* gB[2];
  int offB[2];
#pragma unroll
  for (int p = 0; p < 2; ++p) {
    const int c = tid + p * 256;
    const int r = c >> 3;
    const int sc = ((c & 7) ^ (r & 7)) * 8;
    gB[p] = W + (size_t)(n0 + r) * K + sc;
    offB[p] = c * 8;
  }

  f32x4 acc[4][2];
#pragma unroll
  for (int i = 0; i < 4; ++i)
#pragma unroll
    for (int j = 0; j < 2; ++j) acc[i][j] = (f32x4){0.f, 0.f, 0.f, 0.f};

#pragma unroll
  for (int p = 0; p < 4; ++p) gl_lds16(gA[p], &As[0][offA[p]]);
#pragma unroll
  for (int p = 0; p < 2; ++p) gl_lds16(gB[p], &Bs[0][offB[p]]);

  const int NIT = K >> 6;
  for (int it = 0; it < NIT; ++it) {
    __syncthreads();
    const int cur = it & 1;
    if (it + 1 < NIT) {
      const int kt = (it + 1) << 6;
#pragma unroll
      for (int p = 0; p < 4; ++p) gl_lds16(gA[p] + kt, &As[cur ^ 1][offA[p]]);
#pragma unroll
      for (int p = 0; p < 2; ++p) gl_lds16(gB[p] + kt, &Bs[cur ^ 1][offB[p]]);
    }
    const unsigned short* Ac = As[cur];
    const unsigned short* Bc = Bs[cur];
#pragma unroll
    for (int kc = 0; kc < 2; ++kc) {
      bf16x8 af[4], bfr[2];
#pragma unroll
      for (int i = 0; i < 4; ++i)
        af[i] = *(const bf16x8*)&Ac[(wy * 64 + i * 16 + l15) * 64 + ((kc * 4 + quad) ^ xr) * 8];
#pragma unroll
      for (int j = 0; j < 2; ++j)
        bfr[j] = *(const bf16x8*)&Bc[(wx * 32 + j * 16 + l15) * 64 + ((kc * 4 + quad) ^ xr) * 8];
#pragma unroll
      for (int i = 0; i < 4; ++i)
#pragma unroll
        for (int j = 0; j < 2; ++j)
          acc[i][j] = __builtin_amdgcn_mfma_f32_16x16x32_bf16(af[i], bfr[j], acc[i][j], 0, 0, 0);
    }
  }

#pragma unroll
  for (int i = 0; i < 4; ++i) {
    const int row = m0 + wy * 64 + i * 16 + quad * 4;
#pragma unroll
    for (int j = 0; j < 2; ++j) {
      const int col = n0 + wx * 32 + j * 16 + l15;
      const float bv = bias[col];
#pragma unroll
      for (int r = 0; r < 4; ++r)
        Cf[(size_t)(row + r) * N + col] = acc[i][j][r] + bv;
    }
  }
}

// ---------------- flash attention v18: 4-wave q x kv split (R22 WIN) -------
__global__ __launch_bounds__(256, 3) void attn_fwd(const unsigned short* __restrict__ qkv,
                                                   const unsigned short* __restrict__ vt,
                                                   unsigned short* __restrict__ o) {
  __shared__ unsigned short Ks[2][64 * 64];
  __shared__ unsigned short Vs[2][64 * 64];
  __shared__ unsigned short pbuf[4][2][16 * 40];  // [wave][subtile][16 x (32+8)]
  const int tid  = threadIdx.x;
  const int lane = tid & 63;
  const int w    = tid >> 6;          // 4 waves
  const int wq   = w & 1;             // q-half (32 q)
  const int wk   = w >> 1;            // kv-half (32 kv)
  const int l15  = lane & 15, quad = lane >> 4;
  const int xr   = l15 & 7;
  const int bh = blockIdx.x, b = bh >> 4, h = bh & 15;
  const int y  = (int)blockIdx.y;
  const int qt = (y < 16) ? y : 47 - y;  // per-CU balanced (R21)
  const int q0 = qt * 64;
  const int T = qt + 1;
  const int qs0 = q0 + wq * 32;       // subtile 0 base
  const int qs1 = qs0 + 16;           // subtile 1 base

  const unsigned short* gKd[2];
  const unsigned short* gVd[2];
  int doff[2];
#pragma unroll
  for (int p = 0; p < 2; ++p) {
    const int c = tid + p * 256;
    const int r = c >> 3;
    const int sc = ((c & 7) ^ (r & 7)) * 8;
    gKd[p] = qkv + (size_t)(b * 2048 + r) * 3072 + 1024 + h * 64 + sc;
    gVd[p] = vt + (size_t)(bh * 64 + r) * 2048 + sc;
    doff[p] = c * 8;
  }

  const unsigned short* qr0 = qkv + (size_t)(b * 2048 + qs0 + l15) * 3072 + h * 64;
  const unsigned short* qr1 = qkv + (size_t)(b * 2048 + qs1 + l15) * 3072 + h * 64;
  const bf16x8 bq[2][2] = {
    { *(const bf16x8*)(qr0 + quad * 8), *(const bf16x8*)(qr0 + 32 + quad * 8) },
    { *(const bf16x8*)(qr1 + quad * 8), *(const bf16x8*)(qr1 + 32 + quad * 8) } };

  bf16x8 vones;
#pragma unroll
  for (int k = 0; k < 8; ++k) vones[k] = (short)0x3F80;  // bf16 1.0

  f32x4 acc[2][4];   // [subtile][d-tile], PARTIAL over this wave's kv-half
#pragma unroll
  for (int i = 0; i < 2; ++i)
#pragma unroll
    for (int j = 0; j < 4; ++j) acc[i][j] = (f32x4){0.f, 0.f, 0.f, 0.f};
  f32x4 accL[2] = {(f32x4){0.f, 0.f, 0.f, 0.f}, (f32x4){0.f, 0.f, 0.f, 0.f}};

  unsigned short* P0 = pbuf[w][0];
  unsigned short* P1 = pbuf[w][1];

#pragma unroll
  for (int p = 0; p < 2; ++p) {
    gl_lds16(gKd[p], &Ks[0][doff[p]]);
    gl_lds16(gVd[p], &Vs[0][doff[p]]);
  }

  for (int t = 0; t < T; ++t) {
    __syncthreads();  // drains DMA for buf(t&1)
    const int cur = t & 1;
    if (t + 1 < T) {
      const size_t ko = (size_t)(t + 1) * 64 * 3072;
      const int vo = (t + 1) * 64;
#pragma unroll
      for (int p = 0; p < 2; ++p) {
        gl_lds16(gKd[p] + ko, &Ks[cur ^ 1][doff[p]]);
        gl_lds16(gVd[p] + vo, &Vs[cur ^ 1][doff[p]]);
      }
    }
    const unsigned short* Kc = Ks[cur];
    const unsigned short* Vc = Vs[cur];
    const int kv0 = t * 64 + wk * 32;   // this wave's kv base

    bf16x8 kA[2][2];
#pragma unroll
    for (int n = 0; n < 2; ++n) {
      const int row = wk * 32 + n * 16 + l15;
      kA[n][0] = *(const bf16x8*)&Kc[row * 64 + ((quad) ^ xr) * 8];
      kA[n][1] = *(const bf16x8*)&Kc[row * 64 + ((4 + quad) ^ xr) * 8];
    }
    f32x4 st[2][2];
#pragma unroll
    for (int s = 0; s < 2; ++s)
#pragma unroll
      for (int n = 0; n < 2; ++n) {
        f32x4 z = (f32x4){0.f, 0.f, 0.f, 0.f};
        z = __builtin_amdgcn_mfma_f32_16x16x32_bf16(kA[n][0], bq[s][0], z, 0, 0, 0);
        z = __builtin_amdgcn_mfma_f32_16x16x32_bf16(kA[n][1], bq[s][1], z, 0, 0, 0);
        st[s][n] = z;
      }
    bf16x8 av[4];
#pragma unroll
    for (int j = 0; j < 4; ++j) {
      const int row = j * 16 + l15;
      av[j] = *(const bf16x8*)&Vc[row * 64 + ((wk * 4 + quad) ^ xr) * 8];
    }
#pragma unroll
    for (int s = 0; s < 2; ++s) {
      unsigned short* P = s ? P1 : P0;
      const int qbase = s ? qs1 : qs0;
      if (kv0 + 31 > qbase) {
        const int qrow = qbase + l15;
#pragma unroll
        for (int n = 0; n < 2; ++n)
#pragma unroll
          for (int r = 0; r < 4; ++r)
            if (kv0 + n * 16 + quad * 4 + r > qrow) st[s][n][r] = -1e30f;
      }
#pragma unroll
      for (int n = 0; n < 2; ++n) {
#pragma unroll
        for (int r = 0; r < 4; ++r) st[s][n][r] = __expf(st[s][n][r]);
        u16x4 pw;
        pw[0] = f2b_trunc(st[s][n][0]); pw[1] = f2b_trunc(st[s][n][1]);
        pw[2] = f2b_trunc(st[s][n][2]); pw[3] = f2b_trunc(st[s][n][3]);
        *(u16x4*)&P[l15 * 40 + n * 16 + quad * 4] = pw;
      }
    }
#pragma unroll
    for (int s = 0; s < 2; ++s) {
      const unsigned short* P = s ? P1 : P0;
      const bf16x8 bp = *(const bf16x8*)&P[l15 * 40 + quad * 8];
      accL[s] = __builtin_amdgcn_mfma_f32_16x16x32_bf16(vones, bp, accL[s], 0, 0, 0);
#pragma unroll
      for (int j = 0; j < 4; ++j)
        acc[s][j] = __builtin_amdgcn_mfma_f32_16x16x32_bf16(av[j], bp, acc[s][j], 0, 0, 0);
    }
  }

  __syncthreads();
  float* cmbA = (float*)&Ks[0][0];   // 16 frags x 256 floats = 16KB = Ks
  float* cmbL = (float*)&Vs[0][0];   // 4 x 64 floats = 1KB
  if (wk == 1) {
#pragma unroll
    for (int s = 0; s < 2; ++s) {
      cmbL[(wq * 2 + s) * 64 + lane] = accL[s][0];
#pragma unroll
      for (int j = 0; j < 4; ++j)
        *(f32x4*)&cmbA[(((wq * 2 + s) * 4 + j) << 8) + lane * 4] = acc[s][j];
    }
  }
  __syncthreads();
  if (wk == 0) {
#pragma unroll
    for (int s = 0; s < 2; ++s) {
      const float lsum = accL[s][0] + cmbL[(wq * 2 + s) * 64 + lane];
      const float inv = 1.0f / lsum;
      const int qrow = (s ? qs1 : qs0) + l15;
      unsigned short* orow = o + (size_t)(b * 2048 + qrow) * 1024 + h * 64;
#pragma unroll
      for (int j = 0; j < 4; ++j) {
        const f32x4 oth = *(const f32x4*)&cmbA[(((wq * 2 + s) * 4 + j) << 8) + lane * 4];
        u16x4 ov;
        ov[0] = f2b((acc[s][j][0] + oth[0]) * inv);
        ov[1] = f2b((acc[s][j][1] + oth[1]) * inv);
        ov[2] = f2b((acc[s][j][2] + oth[2]) * inv);
        ov[3] = f2b((acc[s][j][3] + oth[3]) * inv);
        *(u16x4*)(orow + j * 16 + quad * 4) = ov;
      }
    }
  }
}

// ---------------------------------------------------------------------------
extern "C" void kernel_launch(void* const* d_in, const int* in_sizes, int n_in,
                              void* d_out, int out_size, void* d_ws, size_t ws_size,
                              hipStream_t stream) {
  const float* x       = (const float*)d_in[0];
  // d_in[1] = mask: causal tril by construction; implemented analytically.
  const float* w_qkv_w = (const float*)d_in[2];
  const float* w_qkv_b = (const float*)d_in[3];
  const float* w_o_w   = (const float*)d_in[4];
  const float* w_o_b   = (const float*)d_in[5];
  float* out = (float*)d_out;

  unsigned short* ws    = (unsigned short*)d_ws;
  unsigned short* xb    = ws;                                  // 4096*1024
  unsigned short* wqb   = xb   + (size_t)4096 * 1024;          // 3072*1024
  unsigned short* wob   = wqb  + (size_t)3072 * 1024;          // 1024*1024
  unsigned short* qkvb  = wob  + (size_t)1024 * 1024;          // 4096*3072
  unsigned short* vtb   = qkvb + (size_t)4096 * 3072;          // 2048*2048
  unsigned short* attnb = vtb  + (size_t)2048 * 2048;          // 4096*1024

  cvt_all<<<8192, 256, 0, stream>>>(x, w_qkv_w, w_o_w, xb, wqb, wob);
  gemm8<<<dim3(12, 16), 512, 0, stream>>>(xb, wqb, w_qkv_b, qkvb, vtb, 4096, 3072, 1024, 1024);
  attn_fwd<<<dim3(32, 32), 256, 0, stream>>>(qkvb, vtb, attnb);
  gemm_bt64<<<dim3(16, 32), 256, 0, stream>>>(attnb, wob, w_o_b, out, 4096, 1024, 1024);
}

// Round 9
// 179.232 us; speedup vs baseline: 1.0738x; 1.0738x over previous
//
#include <hip/hip_runtime.h>
#include <cstdint>
#include <cstddef>

// ---------------------------------------------------------------------------
// ChatGPTAttention: x[2,2048,1024] -> QKV proj -> causal MHA (16 heads, dk=64)
//                   -> O proj. bf16 MFMA pipeline, fp32 accumulate.
// Q pre-scaled by 1/8 in QKV-GEMM epilogue; V written transposed there (R14).
// LESSONS: (R5) LDS row stride mult of 8 ushorts. (R6/R8) XOR swizzle for DMA
// LDS. (R11/R15) direct global frags fragment. (R18) split P buffers.
// (R19 FAILED) lag-1 PV spills. (R20 FAILED) direct-global V. (R21 NULL)
// per-CU balancing. (R22 WIN) 4-wave qxkv attn split 44.5->36.5us.
// (R23 NEUTRAL) gemm_bt64 retile. (R24 NEUTRAL/R25 REGRESSION) 8-phase 256^2
// QKV GEMM port: at K=1024 each block has only 16 K-tiles — the deep pipeline
// never amortizes; lockstep barriers added stalls (49.5us vs 41.6 for the
// plain 2-barrier 128^2). DIRECTION DEAD AT THIS SHAPE; gemm_bt REVERTED to
// the proven R14 structure (41.6us / 620 TF measured, R6 profile).
// R26 v19: continue the chain-split ladder that pays (R22): attn 8-wave
// split wq(4) x wk(2), 512 thr/block. Per wave per tile: 2 K-frags, 4 S^T
// MFMA, 8 exp, 2 Pw, 1 Pr, 5 PV MFMA (halved vs R22); per-block LDS traffic
// and grid unchanged; 24 waves/CU; combine identical shape (16 frags = dead
// Ks buf). Register state ~halves -> launch_bounds(512,6).
// ---------------------------------------------------------------------------

typedef __attribute__((ext_vector_type(8))) short bf16x8;   // MFMA A/B frag
typedef __attribute__((ext_vector_type(4))) float f32x4;    // MFMA C/D frag
typedef __attribute__((ext_vector_type(4))) unsigned int u32x4;   // 16B copy
typedef __attribute__((ext_vector_type(4))) unsigned short u16x4; // 8B store
typedef __attribute__((ext_vector_type(8))) unsigned short u16x8; // 16B store

__device__ __forceinline__ unsigned short f2b(float f) {  // RNE f32->bf16
  unsigned int u = __float_as_uint(f);
  u = u + 0x7FFFu + ((u >> 16) & 1u);
  return (unsigned short)(u >> 16);
}
__device__ __forceinline__ unsigned short f2b_trunc(float f) {  // truncate
  return (unsigned short)(__float_as_uint(f) >> 16);
}

// async global->LDS DMA, 16B per lane; LDS dest = wave base + lane*16
__device__ __forceinline__ void gl_lds16(const unsigned short* g, unsigned short* s) {
  __builtin_amdgcn_global_load_lds((const __attribute__((address_space(1))) void*)g,
                                   (__attribute__((address_space(3))) void*)s, 16, 0, 0);
}

// ---------------- fp32 -> bf16, all three inputs in one launch -------------
__global__ __launch_bounds__(256) void cvt_all(const float* __restrict__ x,
                                               const float* __restrict__ wq,
                                               const float* __restrict__ wo,
                                               unsigned short* __restrict__ xb,
                                               unsigned short* __restrict__ wqb,
                                               unsigned short* __restrict__ wob) {
  const int bid = blockIdx.x;
  const float* in;
  unsigned short* out;
  int base;
  if (bid < 4096)      { in = x;  out = xb;  base = bid; }
  else if (bid < 7168) { in = wq; out = wqb; base = bid - 4096; }
  else                 { in = wo; out = wob; base = bid - 7168; }
  const int idx = (base * 256 + threadIdx.x) * 4;
  f32x4 v = *(const f32x4*)(in + idx);
  u16x4 r;
  r[0] = f2b(v[0]); r[1] = f2b(v[1]); r[2] = f2b(v[2]); r[3] = f2b(v[3]);
  *(u16x4*)(out + idx) = r;
}

// ---------------- GEMM: C[M,N] = (A[M,K] * W[N,K]^T + bias) * colscale -----
// 128x128 tile, BK=32, dbuf DMA (32KB LDS). V-column blocks (n0>=2048) write
// transposed into vt as packed u16x4. PROVEN R14 structure (41.6us measured).
__global__ __launch_bounds__(256) void gemm_bt(const unsigned short* __restrict__ A,
                                               const unsigned short* __restrict__ W,
                                               const float* __restrict__ bias,
                                               unsigned short* __restrict__ Cb,
                                               unsigned short* __restrict__ vtb,
                                               int M, int N, int K, int qcols) {
  __shared__ unsigned short As[2][128 * 32];
  __shared__ unsigned short Bs[2][128 * 32];
  const int tid  = threadIdx.x;
  const int lane = tid & 63;
  const int w    = tid >> 6;
  const int wy   = w >> 1, wx = w & 1;
  const int l15  = lane & 15, quad = lane >> 4;
  const int xr2  = (l15 >> 1) & 3;
  const int m0 = blockIdx.y * 128, n0 = blockIdx.x * 128;

  const unsigned short* gA[2];
  const unsigned short* gB[2];
  int off[2];
#pragma unroll
  for (int p = 0; p < 2; ++p) {
    const int c = tid + p * 256;
    const int r = c >> 2;
    const int srcc = (c & 3) ^ ((r >> 1) & 3);
    gA[p] = A + (size_t)(m0 + r) * K + srcc * 8;
    gB[p] = W + (size_t)(n0 + r) * K + srcc * 8;
    off[p] = c * 8;
  }

  f32x4 acc[4][4];
#pragma unroll
  for (int i = 0; i < 4; ++i)
#pragma unroll
    for (int j = 0; j < 4; ++j) acc[i][j] = (f32x4){0.f, 0.f, 0.f, 0.f};

#pragma unroll
  for (int p = 0; p < 2; ++p) {
    gl_lds16(gA[p], &As[0][off[p]]);
    gl_lds16(gB[p], &Bs[0][off[p]]);
  }

  const int NIT = K >> 5;
  for (int it = 0; it < NIT; ++it) {
    __syncthreads();
    const int cur = it & 1;
    if (it + 1 < NIT) {
      const int kt = (it + 1) << 5;
#pragma unroll
      for (int p = 0; p < 2; ++p) {
        gl_lds16(gA[p] + kt, &As[cur ^ 1][off[p]]);
        gl_lds16(gB[p] + kt, &Bs[cur ^ 1][off[p]]);
      }
    }
    const unsigned short* Ac = As[cur];
    const unsigned short* Bc = Bs[cur];
    bf16x8 af[4], bfr[4];
#pragma unroll
    for (int i = 0; i < 4; ++i)
      af[i] = *(const bf16x8*)&Ac[(wy * 64 + i * 16 + l15) * 32 + (quad ^ xr2) * 8];
#pragma unroll
    for (int j = 0; j < 4; ++j)
      bfr[j] = *(const bf16x8*)&Bc[(wx * 64 + j * 16 + l15) * 32 + (quad ^ xr2) * 8];
#pragma unroll
    for (int i = 0; i < 4; ++i)
#pragma unroll
      for (int j = 0; j < 4; ++j)
        acc[i][j] = __builtin_amdgcn_mfma_f32_16x16x32_bf16(af[i], bfr[j], acc[i][j], 0, 0, 0);
  }

  const bool vblock = (n0 >= 2048);  // block-uniform
#pragma unroll
  for (int i = 0; i < 4; ++i) {
    const int row = m0 + wy * 64 + i * 16 + quad * 4;
#pragma unroll
    for (int j = 0; j < 4; ++j) {
      const int col = n0 + wx * 64 + j * 16 + l15;
      const float bv = bias[col];
      if (!vblock) {
        const float sc = (col < qcols) ? 0.125f : 1.0f;
#pragma unroll
        for (int r = 0; r < 4; ++r)
          Cb[(size_t)(row + r) * N + col] = f2b((acc[i][j][r] + bv) * sc);
      } else {
        const int hd = col - 2048;
        const int bb = row >> 11, s = row & 2047;
        u16x4 ov;
#pragma unroll
        for (int r = 0; r < 4; ++r) ov[r] = f2b(acc[i][j][r] + bv);
        *(u16x4*)(vtb + ((size_t)(bb * 1024 + hd)) * 2048 + s) = ov;
      }
    }
  }
}

// ---------------- GEMM 128x64 tile, fp32 out (O-projection) ----------------
// R23 config. Grid (16,32)=512 blocks, LDS 48KB.
__global__ __launch_bounds__(256) void gemm_bt64(const unsigned short* __restrict__ A,
                                                 const unsigned short* __restrict__ W,
                                                 const float* __restrict__ bias,
                                                 float* __restrict__ Cf,
                                                 int M, int N, int K) {
  __shared__ unsigned short As[2][128 * 64];
  __shared__ unsigned short Bs[2][64 * 64];
  const int tid  = threadIdx.x;
  const int lane = tid & 63;
  const int w    = tid >> 6;
  const int wy   = w >> 1, wx = w & 1;
  const int l15  = lane & 15, quad = lane >> 4;
  const int xr   = l15 & 7;
  const int m0 = blockIdx.y * 128, n0 = blockIdx.x * 64;

  const unsigned short* gA[4];
  int offA[4];
#pragma unroll
  for (int p = 0; p < 4; ++p) {
    const int c = tid + p * 256;
    const int r = c >> 3;
    const int sc = ((c & 7) ^ (r & 7)) * 8;
    gA[p] = A + (size_t)(m0 + r) * K + sc;
    offA[p] = c * 8;
  }
  const unsigned short* gB[2];
  int offB[2];
#pragma unroll
  for (int p = 0; p < 2; ++p) {
    const int c = tid + p * 256;
    const int r = c >> 3;
    const int sc = ((c & 7) ^ (r & 7)) * 8;
    gB[p] = W + (size_t)(n0 + r) * K + sc;
    offB[p] = c * 8;
  }

  f32x4 acc[4][2];
#pragma unroll
  for (int i = 0; i < 4; ++i)
#pragma unroll
    for (int j = 0; j < 2; ++j) acc[i][j] = (f32x4){0.f, 0.f, 0.f, 0.f};

#pragma unroll
  for (int p = 0; p < 4; ++p) gl_lds16(gA[p], &As[0][offA[p]]);
#pragma unroll
  for (int p = 0; p < 2; ++p) gl_lds16(gB[p], &Bs[0][offB[p]]);

  const int NIT = K >> 6;
  for (int it = 0; it < NIT; ++it) {
    __syncthreads();
    const int cur = it & 1;
    if (it + 1 < NIT) {
      const int kt = (it + 1) << 6;
#pragma unroll
      for (int p = 0; p < 4; ++p) gl_lds16(gA[p] + kt, &As[cur ^ 1][offA[p]]);
#pragma unroll
      for (int p = 0; p < 2; ++p) gl_lds16(gB[p] + kt, &Bs[cur ^ 1][offB[p]]);
    }
    const unsigned short* Ac = As[cur];
    const unsigned short* Bc = Bs[cur];
#pragma unroll
    for (int kc = 0; kc < 2; ++kc) {
      bf16x8 af[4], bfr[2];
#pragma unroll
      for (int i = 0; i < 4; ++i)
        af[i] = *(const bf16x8*)&Ac[(wy * 64 + i * 16 + l15) * 64 + ((kc * 4 + quad) ^ xr) * 8];
#pragma unroll
      for (int j = 0; j < 2; ++j)
        bfr[j] = *(const bf16x8*)&Bc[(wx * 32 + j * 16 + l15) * 64 + ((kc * 4 + quad) ^ xr) * 8];
#pragma unroll
      for (int i = 0; i < 4; ++i)
#pragma unroll
        for (int j = 0; j < 2; ++j)
          acc[i][j] = __builtin_amdgcn_mfma_f32_16x16x32_bf16(af[i], bfr[j], acc[i][j], 0, 0, 0);
    }
  }

#pragma unroll
  for (int i = 0; i < 4; ++i) {
    const int row = m0 + wy * 64 + i * 16 + quad * 4;
#pragma unroll
    for (int j = 0; j < 2; ++j) {
      const int col = n0 + wx * 32 + j * 16 + l15;
      const float bv = bias[col];
#pragma unroll
      for (int r = 0; r < 4; ++r)
        Cf[(size_t)(row + r) * N + col] = acc[i][j][r] + bv;
    }
  }
}

// ---------------- flash attention v19: 8-wave q x kv split -----------------
// Block = 8 waves (wq in 0..3 x wk in 0..1), 64 q x 64 kv tiles; grid
// (bh 32, y 32), 512 threads. Wave (wq,wk): 16 q x 32 kv. Per wave per tile:
// 2 K-frags, 4 S^T MFMA, 8 exp, 2 Pw, 1 Pr + 4 V-frags (shared per wk), 5 PV
// MFMA — chain halved vs R22's v18; per-block LDS traffic unchanged; 24
// waves/CU. kv-half partials combined once per block via dead K/V buffers
// (16 frags = 16KB = Ks). qt map y<16?y:47-y (R21 neutral). XCD=bh%8.
__global__ __launch_bounds__(512, 6) void attn_fwd(const unsigned short* __restrict__ qkv,
                                                   const unsigned short* __restrict__ vt,
                                                   unsigned short* __restrict__ o) {
  __shared__ unsigned short Ks[2][64 * 64];
  __shared__ unsigned short Vs[2][64 * 64];
  __shared__ unsigned short pbuf[8][16 * 40];  // [wave][16 q x (32+8) kv]
  const int tid  = threadIdx.x;
  const int lane = tid & 63;
  const int w    = tid >> 6;          // 8 waves
  const int wq   = w & 3;             // q-quarter (16 q)
  const int wk   = w >> 2;            // kv-half (32 kv)
  const int l15  = lane & 15, quad = lane >> 4;
  const int xr   = l15 & 7;
  const int bh = blockIdx.x, b = bh >> 4, h = bh & 15;
  const int y  = (int)blockIdx.y;
  const int qt = (y < 16) ? y : 47 - y;  // per-CU balanced (R21)
  const int q0 = qt * 64;
  const int T = qt + 1;
  const int qs = q0 + wq * 16;        // this wave's q base (16 rows)

  // DMA staging: 512 chunks per 64x64 tile / 512 threads = 1/thread/array.
  const int r  = tid >> 3;
  const int sc = ((tid & 7) ^ (r & 7)) * 8;
  const unsigned short* gKd = qkv + (size_t)(b * 2048 + r) * 3072 + 1024 + h * 64 + sc;
  const unsigned short* gVd = vt + (size_t)(bh * 64 + r) * 2048 + sc;
  const int doff = tid * 8;

  const unsigned short* qr = qkv + (size_t)(b * 2048 + qs + l15) * 3072 + h * 64;
  const bf16x8 bq[2] = { *(const bf16x8*)(qr + quad * 8),
                         *(const bf16x8*)(qr + 32 + quad * 8) };

  bf16x8 vones;
#pragma unroll
  for (int k = 0; k < 8; ++k) vones[k] = (short)0x3F80;  // bf16 1.0

  f32x4 acc[4];      // [d-tile], PARTIAL over this wave's kv-half
#pragma unroll
  for (int j = 0; j < 4; ++j) acc[j] = (f32x4){0.f, 0.f, 0.f, 0.f};
  f32x4 accL = (f32x4){0.f, 0.f, 0.f, 0.f};

  unsigned short* P = pbuf[w];

  // prologue: DMA tile 0 -> buf 0
  gl_lds16(gKd, &Ks[0][doff]);
  gl_lds16(gVd, &Vs[0][doff]);

  for (int t = 0; t < T; ++t) {
    __syncthreads();  // drains DMA for buf(t&1)
    const int cur = t & 1;
    if (t + 1 < T) {
      const size_t ko = (size_t)(t + 1) * 64 * 3072;
      const int vo = (t + 1) * 64;
      gl_lds16(gKd + ko, &Ks[cur ^ 1][doff]);
      gl_lds16(gVd + vo, &Vs[cur ^ 1][doff]);
    }
    const unsigned short* Kc = Ks[cur];
    const unsigned short* Vc = Vs[cur];
    const int kv0 = t * 64 + wk * 32;   // this wave's kv base

    // ---- S^T[kv][q] = K Q^T, this wave's 32 kv x 16 q ----
    f32x4 st[2];
#pragma unroll
    for (int n = 0; n < 2; ++n) {
      const int row = wk * 32 + n * 16 + l15;
      const bf16x8 kA0 = *(const bf16x8*)&Kc[row * 64 + ((quad) ^ xr) * 8];
      const bf16x8 kA1 = *(const bf16x8*)&Kc[row * 64 + ((4 + quad) ^ xr) * 8];
      f32x4 z = (f32x4){0.f, 0.f, 0.f, 0.f};
      z = __builtin_amdgcn_mfma_f32_16x16x32_bf16(kA0, bq[0], z, 0, 0, 0);
      z = __builtin_amdgcn_mfma_f32_16x16x32_bf16(kA1, bq[1], z, 0, 0, 0);
      st[n] = z;
    }
    // ---- V^T A-frags for this kv-half ----
    bf16x8 av[4];
#pragma unroll
    for (int j = 0; j < 4; ++j) {
      const int row = j * 16 + l15;
      av[j] = *(const bf16x8*)&Vc[row * 64 + ((wk * 4 + quad) ^ xr) * 8];
    }
    // ---- mask/exp + P write ----
    if (kv0 + 31 > qs) {
      const int qrow = qs + l15;
#pragma unroll
      for (int n = 0; n < 2; ++n)
#pragma unroll
        for (int rr = 0; rr < 4; ++rr)
          if (kv0 + n * 16 + quad * 4 + rr > qrow) st[n][rr] = -1e30f;
    }
#pragma unroll
    for (int n = 0; n < 2; ++n) {
#pragma unroll
      for (int rr = 0; rr < 4; ++rr) st[n][rr] = __expf(st[n][rr]);
      u16x4 pw;
      pw[0] = f2b_trunc(st[n][0]); pw[1] = f2b_trunc(st[n][1]);
      pw[2] = f2b_trunc(st[n][2]); pw[3] = f2b_trunc(st[n][3]);
      *(u16x4*)&P[l15 * 40 + n * 16 + quad * 4] = pw;
    }
    // ---- Pr + PV (K=32 contraction) ----
    {
      const bf16x8 bp = *(const bf16x8*)&P[l15 * 40 + quad * 8];
      accL = __builtin_amdgcn_mfma_f32_16x16x32_bf16(vones, bp, accL, 0, 0, 0);
#pragma unroll
      for (int j = 0; j < 4; ++j)
        acc[j] = __builtin_amdgcn_mfma_f32_16x16x32_bf16(av[j], bp, acc[j], 0, 0, 0);
    }
  }

  // ---- cross-wave kv-half combine (once per block; K/V buffers dead) ----
  __syncthreads();
  float* cmbA = (float*)&Ks[0][0];   // 16 frags x 1KB = 16KB = Ks
  float* cmbL = (float*)&Vs[0][0];   // 4 x 64 floats = 1KB
  if (wk == 1) {
    cmbL[wq * 64 + lane] = accL[0];
#pragma unroll
    for (int j = 0; j < 4; ++j)
      *(f32x4*)&cmbA[((wq * 4 + j) << 8) + lane * 4] = acc[j];
  }
  __syncthreads();
  if (wk == 0) {
    const float lsum = accL[0] + cmbL[wq * 64 + lane];
    const float inv = 1.0f / lsum;
    const int qrow = qs + l15;
    unsigned short* orow = o + (size_t)(b * 2048 + qrow) * 1024 + h * 64;
#pragma unroll
    for (int j = 0; j < 4; ++j) {
      const f32x4 oth = *(const f32x4*)&cmbA[((wq * 4 + j) << 8) + lane * 4];
      u16x4 ov;
      ov[0] = f2b((acc[j][0] + oth[0]) * inv);
      ov[1] = f2b((acc[j][1] + oth[1]) * inv);
      ov[2] = f2b((acc[j][2] + oth[2]) * inv);
      ov[3] = f2b((acc[j][3] + oth[3]) * inv);
      *(u16x4*)(orow + j * 16 + quad * 4) = ov;
    }
  }
}

// ---------------------------------------------------------------------------
extern "C" void kernel_launch(void* const* d_in, const int* in_sizes, int n_in,
                              void* d_out, int out_size, void* d_ws, size_t ws_size,
                              hipStream_t stream) {
  const float* x       = (const float*)d_in[0];
  // d_in[1] = mask: causal tril by construction; implemented analytically.
  const float* w_qkv_w = (const float*)d_in[2];
  const float* w_qkv_b = (const float*)d_in[3];
  const float* w_o_w   = (const float*)d_in[4];
  const float* w_o_b   = (const float*)d_in[5];
  float* out = (float*)d_out;

  unsigned short* ws    = (unsigned short*)d_ws;
  unsigned short* xb    = ws;                                  // 4096*1024
  unsigned short* wqb   = xb   + (size_t)4096 * 1024;          // 3072*1024
  unsigned short* wob   = wqb  + (size_t)3072 * 1024;          // 1024*1024
  unsigned short* qkvb  = wob  + (size_t)1024 * 1024;          // 4096*3072
  unsigned short* vtb   = qkvb + (size_t)4096 * 3072;          // 2048*2048
  unsigned short* attnb = vtb  + (size_t)2048 * 2048;          // 4096*1024

  cvt_all<<<8192, 256, 0, stream>>>(x, w_qkv_w, w_o_w, xb, wqb, wob);
  gemm_bt<<<dim3(24, 32), 256, 0, stream>>>(xb, wqb, w_qkv_b, qkvb, vtb, 4096, 3072, 1024, 1024);
  attn_fwd<<<dim3(32, 32), 512, 0, stream>>>(qkvb, vtb, attnb);
  gemm_bt64<<<dim3(16, 32), 256, 0, stream>>>(attnb, wob, w_o_b, out, 4096, 1024, 1024);
}